// Round 5
// baseline (134.667 us; speedup 1.0000x reference)
//
#include <hip/hip_runtime.h>

#define NPTS     16384
#define G        20
#define G2       400
#define ORIGIN   -5.0f
#define INV_CELL 2.0f
#define D2MAX    0.25f     // EPS^2 sentinel: contributes exactly 0 after sqrt
#define QPW      8         // queries per worklist entry

#define KNN_GRID  2048     // blocks; grid-stride over worklist entries
#define KNN_BLOCK 256      // 4 waves per block

// ---- ws layout (bytes) ----
#define OFF_COUNTS   0u        // u32[8192]
#define OFF_STARTS   32768u    // u32[8192]
#define OFF_CURSORS  65536u    // u32[8192]
#define OFF_WLCNT    98304u    // u32 (written by scan)
#define OFF_WL       98432u    // int2[12288] (worst case 10048 entries)
#define OFF_PTS      262144u   // float4[16384], cell-sorted
#define OFF_CID      524288u   // u32[16384]
#define OFF_PART     589824u   // float[10048] per-entry partials
#define WS_REQUIRED  630016u

__global__ __launch_bounds__(256) void prep_hist_kernel(const float* __restrict__ q,
                                                        unsigned char* ws) {
  unsigned* counts  = (unsigned*)(ws + OFF_COUNTS);
  unsigned* cid_arr = (unsigned*)(ws + OFF_CID);
  const int i = blockIdx.x * 256 + threadIdx.x;   // 16384 threads
  const float x = q[3 * i + 0], y = q[3 * i + 1], z = q[3 * i + 2];
  int cx = (int)floorf((x - ORIGIN) * INV_CELL); cx = min(max(cx, 0), G - 1);
  int cy = (int)floorf((y - ORIGIN) * INV_CELL); cy = min(max(cy, 0), G - 1);
  int cz = (int)floorf((z - ORIGIN) * INV_CELL); cz = min(max(cz, 0), G - 1);
  const unsigned cid = (unsigned)((cx * G + cy) * G + cz);
  cid_arr[i] = cid;
  atomicAdd(counts + cid, 1u);
}

// Single block: prefix-sum counts -> starts; zero cursors; emit worklist of
// (group start, cell<<4 | cnt) entries with cnt <= 8; write entry count.
__global__ __launch_bounds__(1024) void prep_scan_kernel(unsigned char* ws) {
  unsigned* counts  = (unsigned*)(ws + OFF_COUNTS);
  unsigned* starts  = (unsigned*)(ws + OFF_STARTS);
  unsigned* cursors = (unsigned*)(ws + OFF_CURSORS);
  unsigned* wlcnt   = (unsigned*)(ws + OFF_WLCNT);
  int2*     wl      = (int2*)(ws + OFF_WL);

  __shared__ unsigned scnt[1024], sent[1024];
  const int t = threadIdx.x;
  unsigned c8[8];
  unsigned mycnt = 0, myent = 0;
#pragma unroll
  for (int i = 0; i < 8; ++i) {
    c8[i] = counts[t * 8 + i];
    mycnt += c8[i];
    myent += (c8[i] + 7u) >> 3;
  }
  scnt[t] = mycnt; sent[t] = myent;
  __syncthreads();
  for (int off = 1; off < 1024; off <<= 1) {
    unsigned a = 0, b = 0;
    if (t >= off) { a = scnt[t - off]; b = sent[t - off]; }
    __syncthreads();
    scnt[t] += a; sent[t] += b;
    __syncthreads();
  }
  unsigned run  = scnt[t] - mycnt;   // exclusive prefixes
  unsigned erun = sent[t] - myent;
#pragma unroll
  for (int i = 0; i < 8; ++i) {
    const int c = t * 8 + i;
    starts[c]  = run;
    cursors[c] = 0u;
    const unsigned n  = c8[i];
    const unsigned ne = (n + 7u) >> 3;
    for (unsigned g = 0; g < ne; ++g) {
      const unsigned rem = n - 8u * g;
      const unsigned cnt = rem < 8u ? rem : 8u;
      wl[erun + g] = make_int2((int)(run + 8u * g), (c << 4) | (int)cnt);
    }
    erun += ne;
    run  += n;
  }
  if (t == 1023) *wlcnt = sent[1023];
}

__global__ __launch_bounds__(256) void prep_scatter_kernel(const float* __restrict__ q,
                                                           unsigned char* ws) {
  const unsigned* starts  = (const unsigned*)(ws + OFF_STARTS);
  unsigned*       cursors = (unsigned*)(ws + OFF_CURSORS);
  const unsigned* cid_arr = (const unsigned*)(ws + OFF_CID);
  float4*         pts     = (float4*)(ws + OFF_PTS);
  const int i = blockIdx.x * 256 + threadIdx.x;   // 16384 threads
  const unsigned cid = cid_arr[i];
  const unsigned pos = starts[cid] + atomicAdd(cursors + cid, 1u);
  pts[pos] = make_float4(q[3 * i + 0], q[3 * i + 1], q[3 * i + 2], 0.0f);
}

// One BLOCK (4 waves) per worklist entry. All 4 waves share all 9 z-column
// ranges round-robin (wave w takes 64-chunks at j = rs+64w, stride 256) ->
// near-perfect intra-entry balance. Per lane: private sorted top-5 per query
// (branchless med-shift). Per wave: exact wave-local top-8 per query via
// butterfly extract-min -> LDS. Wave 0: merge 4x8 per query, accumulate.
__global__ __launch_bounds__(KNN_BLOCK) void knn_cells_kernel(unsigned char* ws) {
  const unsigned* starts = (const unsigned*)(ws + OFF_STARTS);
  const int2*     wl     = (const int2*)(ws + OFF_WL);
  const float4*   pts    = (const float4*)(ws + OFF_PTS);
  float*          part   = (float*)(ws + OFF_PART);
  const int wlc = (int)*(const unsigned*)(ws + OFF_WLCNT);

  __shared__ float M[4][QPW][8];   // per-wave sorted top-8 per query (1 KB)

  const int lane = threadIdx.x & 63;
  const int wave = threadIdx.x >> 6;

  // column visit order {dx,dy}: own column first, then faces, then corners
  const unsigned DXC = 10569u;  // {0,1,-1,0,0,1,1,-1,-1}
  const unsigned DYC = 34965u;  // {0,0,0,1,-1,1,-1,1,-1}

  for (int e = blockIdx.x; e < wlc; e += KNN_GRID) {
    const int2 ent   = wl[e];
    const int qstart = ent.x;
    const int cell   = ent.y >> 4;
    const int cnt    = ent.y & 15;

    float qx[QPW], qy[QPW], qz[QPW];
#pragma unroll
    for (int k = 0; k < QPW; ++k) {
      if (k < cnt) {
        const float4 Q = pts[qstart + k];
        qx[k] = Q.x; qy[k] = Q.y; qz[k] = Q.z;
      } else {  // dummy query far away: never passes threshold
        qx[k] = 1.0e4f; qy[k] = 1.0e4f; qz[k] = 1.0e4f;
      }
    }

    float P[QPW][5];
#pragma unroll
    for (int k = 0; k < QPW; ++k)
#pragma unroll
      for (int s = 0; s < 5; ++s) P[k][s] = D2MAX;

    const int cx  = cell / G2;
    const int rem = cell - cx * G2;
    const int cy  = rem / G;
    const int cz  = rem - cy * G;
    const int zlo = cz > 0 ? cz - 1 : 0;
    const int zhi = cz < G - 1 ? cz + 1 : G - 1;

    // Prefetch all 9 column range bounds (independent loads)
    int rs[9], re[9];
#pragma unroll
    for (int r = 0; r < 9; ++r) {
      const int dx = (int)((DXC >> (2 * r)) & 3u) - 1;
      const int dy = (int)((DYC >> (2 * r)) & 3u) - 1;
      const int nx = cx + dx, ny = cy + dy;
      if ((unsigned)nx < (unsigned)G && (unsigned)ny < (unsigned)G) {
        const int colbase = (nx * G + ny) * G;
        rs[r] = (int)starts[colbase + zlo];
        re[r] = (int)starts[colbase + zhi + 1];
      } else {
        rs[r] = 0; re[r] = 0;
      }
    }

#pragma unroll
    for (int r = 0; r < 9; ++r) {
      for (int j = rs[r] + wave * 64; j < re[r]; j += 256) {
        int idx = j + lane;
        const bool val = idx < re[r];
        if (!val) idx = re[r] - 1;
        const float4 Pt = pts[idx];
        float d2[QPW];
#pragma unroll
        for (int k = 0; k < QPW; ++k) {
          const float ddx = qx[k] - Pt.x;
          const float ddy = qy[k] - Pt.y;
          const float ddz = qz[k] - Pt.z;
          const float dd = fmaf(ddz, ddz, fmaf(ddy, ddy, ddx * ddx));
          d2[k] = val ? dd : 1.0e9f;   // self -> exactly 0, excluded below
        }
#pragma unroll
        for (int k = 0; k < QPW; ++k) {
          const float v = d2[k];
          if (v < P[k][4] && v != 0.0f) {   // lane-parallel masked insert
            P[k][4] = fmaxf(P[k][3], fminf(v, P[k][4]));
            P[k][3] = fmaxf(P[k][2], fminf(v, P[k][3]));
            P[k][2] = fmaxf(P[k][1], fminf(v, P[k][2]));
            P[k][1] = fmaxf(P[k][0], fminf(v, P[k][1]));
            P[k][0] = fminf(P[k][0], v);
          }
        }
      }
    }

    // Per-wave: exact top-8 of this wave's subset per query -> LDS (sorted)
#pragma unroll
    for (int k = 0; k < QPW; ++k) {
      if (k < cnt) {
        float a0 = P[k][0], a1 = P[k][1], a2 = P[k][2], a3 = P[k][3], a4 = P[k][4];
#pragma unroll
        for (int rr = 0; rr < 8; ++rr) {
          float m = a0;
          m = fminf(m, __shfl_xor(m, 1));
          m = fminf(m, __shfl_xor(m, 2));
          m = fminf(m, __shfl_xor(m, 4));
          m = fminf(m, __shfl_xor(m, 8));
          m = fminf(m, __shfl_xor(m, 16));
          m = fminf(m, __shfl_xor(m, 32));
          if (lane == 0) M[wave][k][rr] = m;
          const unsigned long long bal = __ballot(a0 == m);
          const int first = __ffsll(bal) - 1;
          const bool adv = (lane == first);
          a0 = adv ? a1 : a0;
          a1 = adv ? a2 : a1;
          a2 = adv ? a3 : a2;
          a3 = adv ? a4 : a3;
          a4 = adv ? D2MAX : a4;
        }
      }
    }
    __syncthreads();

    // Wave 0: merge the 4 sorted-8 lists per query (exact top-8 of union)
    if (wave == 0) {
      float accE = 0.0f;
#pragma unroll
      for (int k = 0; k < QPW; ++k) {
        if (k < cnt) {
          float v = (lane < 32) ? M[lane >> 3][k][lane & 7] : D2MAX;
#pragma unroll
          for (int rr = 0; rr < 8; ++rr) {
            float m = v;
            m = fminf(m, __shfl_xor(m, 1));
            m = fminf(m, __shfl_xor(m, 2));
            m = fminf(m, __shfl_xor(m, 4));
            m = fminf(m, __shfl_xor(m, 8));
            m = fminf(m, __shfl_xor(m, 16));
            m = fminf(m, __shfl_xor(m, 32));
            accE += 0.5f - sqrtf(m);   // m <= 0.25 always; sentinel -> +0
            const unsigned long long bal = __ballot(v == m);
            const int first = __ffsll(bal) - 1;
            if (lane == first) v = D2MAX;
          }
        }
      }
      if (lane == 0) part[e] = accE;
    }
    __syncthreads();   // protect M before next entry's writes
  }
}

__global__ __launch_bounds__(256) void final_reduce2_kernel(const unsigned char* ws,
                                                            float* __restrict__ out) {
  const float* part = (const float*)(ws + OFF_PART);
  const int wlc = (int)*(const unsigned*)(ws + OFF_WLCNT);
  const int tid = threadIdx.x;
  float v = 0.0f;
  for (int i = tid; i < wlc; i += 256) v += part[i];
#pragma unroll
  for (int off = 1; off < 64; off <<= 1) v += __shfl_xor(v, off);
  __shared__ float r[4];
  if ((tid & 63) == 0) r[tid >> 6] = v;
  __syncthreads();
  if (tid == 0) out[0] = (r[0] + r[1] + r[2] + r[3]) * (1.0f / (float)NPTS);
}

// ---------------- v2 fallback (proven) if ws is too small ----------------
#define FB_TILE 2048
__global__ __launch_bounds__(512) void knn_loss_kernel(
    const float* __restrict__ q, float* __restrict__ block_sum) {
  __shared__ float4 tile[FB_TILE];
  __shared__ float  wsum[8];
  const int tid = threadIdx.x, lane = tid & 63, wave = tid >> 6;
  const int qbase = blockIdx.x * 32 + wave * 4;
  float qx[4], qy[4], qz[4], qq[4];
#pragma unroll
  for (int k = 0; k < 4; ++k) {
    const float x = q[3 * (qbase + k) + 0];
    const float y = q[3 * (qbase + k) + 1];
    const float z = q[3 * (qbase + k) + 2];
    qx[k] = x; qy[k] = y; qz[k] = z;
    qq[k] = fmaf(z, z, fmaf(y, y, x * x));
  }
  float L[4][8];
#pragma unroll
  for (int k = 0; k < 4; ++k)
#pragma unroll
    for (int s = 0; s < 8; ++s) L[k][s] = D2MAX;
  for (int t = 0; t < NPTS / FB_TILE; ++t) {
    const int tb = t * FB_TILE;
#pragma unroll
    for (int s2 = 0; s2 < FB_TILE / 512; ++s2) {
      const int p = s2 * 512 + tid, gp = tb + p;
      const float x = q[3 * gp], y = q[3 * gp + 1], z = q[3 * gp + 2];
      tile[p] = make_float4(x, y, z, fmaf(z, z, fmaf(y, y, x * x)));
    }
    __syncthreads();
#pragma unroll 2
    for (int s = 0; s < FB_TILE / 64; ++s) {
      const float4 p = tile[s * 64 + lane];
      float d2[4];
#pragma unroll
      for (int k = 0; k < 4; ++k) {
        const float dt = fmaf(qx[k], p.x, fmaf(qy[k], p.y, qz[k] * p.z));
        d2[k] = fmaf(-2.0f, dt, qq[k] + p.w);
      }
      unsigned long long m[4];
#pragma unroll
      for (int k = 0; k < 4; ++k) m[k] = __ballot(d2[k] < L[k][7]);
      if (m[0] | m[1] | m[2] | m[3]) {
        const int jb = tb + s * 64;
#pragma unroll
        for (int k = 0; k < 4; ++k) {
          unsigned long long mk = m[k];
          while (mk) {
            const int i = __ffsll(mk) - 1;
            mk &= mk - 1;
            const float v = __shfl(d2[k], i);
            if ((jb + i) != (qbase + k) && v < L[k][7]) {
              L[k][7] = fmaxf(L[k][6], fminf(v, L[k][7]));
              L[k][6] = fmaxf(L[k][5], fminf(v, L[k][6]));
              L[k][5] = fmaxf(L[k][4], fminf(v, L[k][5]));
              L[k][4] = fmaxf(L[k][3], fminf(v, L[k][4]));
              L[k][3] = fmaxf(L[k][2], fminf(v, L[k][3]));
              L[k][2] = fmaxf(L[k][1], fminf(v, L[k][2]));
              L[k][1] = fmaxf(L[k][0], fminf(v, L[k][1]));
              L[k][0] = fminf(L[k][0], v);
            }
          }
        }
      }
    }
    __syncthreads();
  }
  float acc = 0.0f;
#pragma unroll
  for (int k = 0; k < 4; ++k)
#pragma unroll
    for (int s = 0; s < 8; ++s) acc += 0.5f - sqrtf(fmaxf(L[k][s], 0.0f));
  if (lane == 0) wsum[wave] = acc;
  __syncthreads();
  if (tid == 0) {
    float s = 0.0f;
#pragma unroll
    for (int w = 0; w < 8; ++w) s += wsum[w];
    block_sum[blockIdx.x] = s;
  }
}

__global__ __launch_bounds__(256) void final_reduce_kernel(
    const float* __restrict__ bs, float* __restrict__ out) {
  const int tid = threadIdx.x;
  float v = bs[tid] + bs[tid + 256];
#pragma unroll
  for (int off = 1; off < 64; off <<= 1) v += __shfl_xor(v, off);
  __shared__ float r[4];
  if ((tid & 63) == 0) r[tid >> 6] = v;
  __syncthreads();
  if (tid == 0) out[0] = (r[0] + r[1] + r[2] + r[3]) * (1.0f / (float)NPTS);
}

extern "C" void kernel_launch(void* const* d_in, const int* in_sizes, int n_in,
                              void* d_out, int out_size, void* d_ws, size_t ws_size,
                              hipStream_t stream) {
  const float* q = (const float*)d_in[0];
  unsigned char* ws = (unsigned char*)d_ws;
  if (ws_size >= WS_REQUIRED) {
    hipMemsetAsync(ws + OFF_COUNTS, 0, 32768, stream);   // counts only
    prep_hist_kernel<<<64, 256, 0, stream>>>(q, ws);
    prep_scan_kernel<<<1, 1024, 0, stream>>>(ws);
    prep_scatter_kernel<<<64, 256, 0, stream>>>(q, ws);
    knn_cells_kernel<<<KNN_GRID, KNN_BLOCK, 0, stream>>>(ws);
    final_reduce2_kernel<<<1, 256, 0, stream>>>(ws, (float*)d_out);
  } else {
    float* block_sum = (float*)d_ws;
    knn_loss_kernel<<<512, 512, 0, stream>>>(q, block_sum);
    final_reduce_kernel<<<1, 256, 0, stream>>>(block_sum, (float*)d_out);
  }
}

// Round 6
// 66.143 us; speedup vs baseline: 2.0360x; 2.0360x over previous
//
#include <hip/hip_runtime.h>

#define NPTS     16384
#define G        20
#define G2       400
#define ORIGIN   -5.0f
#define INV_CELL 2.0f
#define D2MAX    0.25f     // EPS^2 sentinel: contributes exactly 0 after sqrt

#define KNN_GRID  3072     // 12288 waves >= worst-case 12192 entries
#define KNN_BLOCK 256

// ---- ws layout (bytes) ----
#define OFF_COUNTS   0u        // u32[8192]
#define OFF_STARTS   32768u    // u32[8192]
#define OFF_CURSORS  65536u    // u32[8192]
#define OFF_WLCNT    98304u    // u32 (written by scan)
#define OFF_WL       98432u    // int2[12288]  (worst case 12192 entries)
#define OFF_EOFF     196736u   // u32[8192] per-cell entry offset
#define OFF_PTS      262144u   // float4[16384], cell-sorted
#define OFF_CID      524288u   // u32[16384]
#define OFF_PART     589824u   // float[12288] per-entry partials
#define WS_REQUIRED  638976u

__global__ __launch_bounds__(256) void prep_hist_kernel(const float* __restrict__ q,
                                                        unsigned char* ws) {
  unsigned* counts  = (unsigned*)(ws + OFF_COUNTS);
  unsigned* cid_arr = (unsigned*)(ws + OFF_CID);
  const int i = blockIdx.x * 256 + threadIdx.x;   // 16384 threads
  const float x = q[3 * i + 0], y = q[3 * i + 1], z = q[3 * i + 2];
  int cx = (int)floorf((x - ORIGIN) * INV_CELL); cx = min(max(cx, 0), G - 1);
  int cy = (int)floorf((y - ORIGIN) * INV_CELL); cy = min(max(cy, 0), G - 1);
  int cz = (int)floorf((z - ORIGIN) * INV_CELL); cz = min(max(cz, 0), G - 1);
  const unsigned cid = (unsigned)((cx * G + cy) * G + cz);
  cid_arr[i] = cid;
  atomicAdd(counts + cid, 1u);
}

// Single block: prefix-sum counts -> starts; zero cursors; per-cell entry
// offsets (pairs: ne = ceil(n/2)); total entry count. NO serial emit here.
__global__ __launch_bounds__(1024) void prep_scan_kernel(unsigned char* ws) {
  unsigned* counts  = (unsigned*)(ws + OFF_COUNTS);
  unsigned* starts  = (unsigned*)(ws + OFF_STARTS);
  unsigned* cursors = (unsigned*)(ws + OFF_CURSORS);
  unsigned* eoff    = (unsigned*)(ws + OFF_EOFF);
  unsigned* wlcnt   = (unsigned*)(ws + OFF_WLCNT);

  __shared__ unsigned scnt[1024], sent[1024];
  const int t = threadIdx.x;
  unsigned c8[8];
  unsigned mycnt = 0, myent = 0;
#pragma unroll
  for (int i = 0; i < 8; ++i) {
    c8[i] = counts[t * 8 + i];
    mycnt += c8[i];
    myent += (c8[i] + 1u) >> 1;
  }
  scnt[t] = mycnt; sent[t] = myent;
  __syncthreads();
  for (int off = 1; off < 1024; off <<= 1) {
    unsigned a = 0, b = 0;
    if (t >= off) { a = scnt[t - off]; b = sent[t - off]; }
    __syncthreads();
    scnt[t] += a; sent[t] += b;
    __syncthreads();
  }
  unsigned run  = scnt[t] - mycnt;   // exclusive prefixes
  unsigned erun = sent[t] - myent;
#pragma unroll
  for (int i = 0; i < 8; ++i) {
    const int c = t * 8 + i;
    starts[c]  = run;
    cursors[c] = 0u;
    eoff[c]    = erun;
    run  += c8[i];
    erun += (c8[i] + 1u) >> 1;
  }
  if (t == 1023) *wlcnt = sent[1023];
}

// Fused: scatter points into cell-sorted order (all 16384 threads) AND emit
// pair-entries per cell (threads < 8192, parallel over cells).
__global__ __launch_bounds__(256) void prep_scatter_emit_kernel(
    const float* __restrict__ q, unsigned char* ws) {
  const unsigned* counts  = (const unsigned*)(ws + OFF_COUNTS);
  const unsigned* starts  = (const unsigned*)(ws + OFF_STARTS);
  unsigned*       cursors = (unsigned*)(ws + OFF_CURSORS);
  const unsigned* eoff    = (const unsigned*)(ws + OFF_EOFF);
  const unsigned* cid_arr = (const unsigned*)(ws + OFF_CID);
  int2*           wl      = (int2*)(ws + OFF_WL);
  float4*         pts     = (float4*)(ws + OFF_PTS);

  const int i = blockIdx.x * 256 + threadIdx.x;   // 16384 threads
  const unsigned cid = cid_arr[i];
  const unsigned pos = starts[cid] + atomicAdd(cursors + cid, 1u);
  pts[pos] = make_float4(q[3 * i + 0], q[3 * i + 1], q[3 * i + 2], 0.0f);

  if (i < 8192) {   // emit this cell's entries (avg ~1.2, max 65 iters)
    const unsigned n = counts[i];
    if (n) {
      const unsigned base = eoff[i];
      const int st = (int)starts[i];
      const unsigned ne = (n + 1u) >> 1;
      for (unsigned g = 0; g < ne; ++g) {
        const unsigned rem = n - 2u * g;
        const int c2 = rem < 2u ? (int)rem : 2;
        wl[base + g] = make_int2(st + 2 * (int)g, (i << 4) | c2);
      }
    }
  }
}

// ONE WAVE per pair-entry (<=2 queries of one cell). No LDS, no barriers,
// no cross-wave merge. Per lane: private sorted top-5 per query (branchless
// med-shift). Epilogue: exact top-8 per query via 8 butterfly extract-min
// rounds over the 64x5 pool (sentinel 0.25 entries contribute exactly 0).
__global__ __launch_bounds__(KNN_BLOCK) void knn_cells_kernel(unsigned char* ws) {
  const unsigned* starts = (const unsigned*)(ws + OFF_STARTS);
  const int2*     wl     = (const int2*)(ws + OFF_WL);
  const float4*   pts    = (const float4*)(ws + OFF_PTS);
  float*          part   = (float*)(ws + OFF_PART);
  const int wlc = (int)*(const unsigned*)(ws + OFF_WLCNT);

  const int lane = threadIdx.x & 63;
  const int e    = blockIdx.x * (KNN_BLOCK / 64) + (threadIdx.x >> 6);
  if (e >= wlc) return;

  // column visit order {dx,dy}: own column first, then faces, then corners
  const unsigned DXC = 10569u;  // {0,1,-1,0,0,1,1,-1,-1}
  const unsigned DYC = 34965u;  // {0,0,0,1,-1,1,-1,1,-1}

  const int2 ent   = wl[e];
  const int qstart = ent.x;
  const int cell   = ent.y >> 4;
  const int cnt    = ent.y & 15;   // 1 or 2

  float qx[2], qy[2], qz[2];
#pragma unroll
  for (int k = 0; k < 2; ++k) {
    if (k < cnt) {
      const float4 Q = pts[qstart + k];
      qx[k] = Q.x; qy[k] = Q.y; qz[k] = Q.z;
    } else {  // dummy query far away: never passes threshold
      qx[k] = 1.0e4f; qy[k] = 1.0e4f; qz[k] = 1.0e4f;
    }
  }

  float P[2][5];
#pragma unroll
  for (int k = 0; k < 2; ++k)
#pragma unroll
    for (int s = 0; s < 5; ++s) P[k][s] = D2MAX;

  const int cx  = cell / G2;
  const int rem = cell - cx * G2;
  const int cy  = rem / G;
  const int cz  = rem - cy * G;
  const int zlo = cz > 0 ? cz - 1 : 0;
  const int zhi = cz < G - 1 ? cz + 1 : G - 1;

  // Prefetch all 9 column range bounds (independent loads, one latency wall)
  int rs[9], re[9];
#pragma unroll
  for (int r = 0; r < 9; ++r) {
    const int dx = (int)((DXC >> (2 * r)) & 3u) - 1;
    const int dy = (int)((DYC >> (2 * r)) & 3u) - 1;
    const int nx = cx + dx, ny = cy + dy;
    if ((unsigned)nx < (unsigned)G && (unsigned)ny < (unsigned)G) {
      const int colbase = (nx * G + ny) * G;
      rs[r] = (int)starts[colbase + zlo];
      re[r] = (int)starts[colbase + zhi + 1];
    } else {
      rs[r] = 0; re[r] = 0;
    }
  }

#pragma unroll
  for (int r = 0; r < 9; ++r) {
    for (int j = rs[r]; j < re[r]; j += 64) {
      int idx = j + lane;
      const bool val = idx < re[r];
      if (!val) idx = re[r] - 1;
      const float4 Pt = pts[idx];
#pragma unroll
      for (int k = 0; k < 2; ++k) {
        const float ddx = qx[k] - Pt.x;
        const float ddy = qy[k] - Pt.y;
        const float ddz = qz[k] - Pt.z;
        float v = fmaf(ddz, ddz, fmaf(ddy, ddy, ddx * ddx));
        if (!val) v = 1.0e9f;
        if (v < P[k][4] && v != 0.0f) {   // self -> exactly 0, excluded
          P[k][4] = fmaxf(P[k][3], fminf(v, P[k][4]));
          P[k][3] = fmaxf(P[k][2], fminf(v, P[k][3]));
          P[k][2] = fmaxf(P[k][1], fminf(v, P[k][2]));
          P[k][1] = fmaxf(P[k][0], fminf(v, P[k][1]));
          P[k][0] = fminf(P[k][0], v);
        }
      }
    }
  }

  // Epilogue: per query, sum relu-contributions of the 8 smallest of the
  // 64x5 pool. m <= 0.25 always; sentinel -> +0. Ascending -> deterministic.
  float accE = 0.0f;
#pragma unroll
  for (int k = 0; k < 2; ++k) {
    if (k < cnt) {
      float a0 = P[k][0], a1 = P[k][1], a2 = P[k][2], a3 = P[k][3], a4 = P[k][4];
#pragma unroll
      for (int rr = 0; rr < 8; ++rr) {
        float m = a0;
        m = fminf(m, __shfl_xor(m, 1));
        m = fminf(m, __shfl_xor(m, 2));
        m = fminf(m, __shfl_xor(m, 4));
        m = fminf(m, __shfl_xor(m, 8));
        m = fminf(m, __shfl_xor(m, 16));
        m = fminf(m, __shfl_xor(m, 32));
        accE += 0.5f - sqrtf(m);
        const unsigned long long bal = __ballot(a0 == m);
        const int first = __ffsll(bal) - 1;
        const bool adv = (lane == first);
        a0 = adv ? a1 : a0;
        a1 = adv ? a2 : a1;
        a2 = adv ? a3 : a2;
        a3 = adv ? a4 : a3;
        a4 = adv ? D2MAX : a4;
      }
    }
  }

  if (lane == 0) part[e] = accE;
}

__global__ __launch_bounds__(256) void final_reduce2_kernel(const unsigned char* ws,
                                                            float* __restrict__ out) {
  const float* part = (const float*)(ws + OFF_PART);
  const int wlc = (int)*(const unsigned*)(ws + OFF_WLCNT);
  const int tid = threadIdx.x;
  float v = 0.0f;
  for (int i = tid; i < wlc; i += 256) v += part[i];
#pragma unroll
  for (int off = 1; off < 64; off <<= 1) v += __shfl_xor(v, off);
  __shared__ float r[4];
  if ((tid & 63) == 0) r[tid >> 6] = v;
  __syncthreads();
  if (tid == 0) out[0] = (r[0] + r[1] + r[2] + r[3]) * (1.0f / (float)NPTS);
}

// ---------------- v2 fallback (proven) if ws is too small ----------------
#define FB_TILE 2048
__global__ __launch_bounds__(512) void knn_loss_kernel(
    const float* __restrict__ q, float* __restrict__ block_sum) {
  __shared__ float4 tile[FB_TILE];
  __shared__ float  wsum[8];
  const int tid = threadIdx.x, lane = tid & 63, wave = tid >> 6;
  const int qbase = blockIdx.x * 32 + wave * 4;
  float qx[4], qy[4], qz[4], qq[4];
#pragma unroll
  for (int k = 0; k < 4; ++k) {
    const float x = q[3 * (qbase + k) + 0];
    const float y = q[3 * (qbase + k) + 1];
    const float z = q[3 * (qbase + k) + 2];
    qx[k] = x; qy[k] = y; qz[k] = z;
    qq[k] = fmaf(z, z, fmaf(y, y, x * x));
  }
  float L[4][8];
#pragma unroll
  for (int k = 0; k < 4; ++k)
#pragma unroll
    for (int s = 0; s < 8; ++s) L[k][s] = D2MAX;
  for (int t = 0; t < NPTS / FB_TILE; ++t) {
    const int tb = t * FB_TILE;
#pragma unroll
    for (int s2 = 0; s2 < FB_TILE / 512; ++s2) {
      const int p = s2 * 512 + tid, gp = tb + p;
      const float x = q[3 * gp], y = q[3 * gp + 1], z = q[3 * gp + 2];
      tile[p] = make_float4(x, y, z, fmaf(z, z, fmaf(y, y, x * x)));
    }
    __syncthreads();
#pragma unroll 2
    for (int s = 0; s < FB_TILE / 64; ++s) {
      const float4 p = tile[s * 64 + lane];
      float d2[4];
#pragma unroll
      for (int k = 0; k < 4; ++k) {
        const float dt = fmaf(qx[k], p.x, fmaf(qy[k], p.y, qz[k] * p.z));
        d2[k] = fmaf(-2.0f, dt, qq[k] + p.w);
      }
      unsigned long long m[4];
#pragma unroll
      for (int k = 0; k < 4; ++k) m[k] = __ballot(d2[k] < L[k][7]);
      if (m[0] | m[1] | m[2] | m[3]) {
        const int jb = tb + s * 64;
#pragma unroll
        for (int k = 0; k < 4; ++k) {
          unsigned long long mk = m[k];
          while (mk) {
            const int i = __ffsll(mk) - 1;
            mk &= mk - 1;
            const float v = __shfl(d2[k], i);
            if ((jb + i) != (qbase + k) && v < L[k][7]) {
              L[k][7] = fmaxf(L[k][6], fminf(v, L[k][7]));
              L[k][6] = fmaxf(L[k][5], fminf(v, L[k][6]));
              L[k][5] = fmaxf(L[k][4], fminf(v, L[k][5]));
              L[k][4] = fmaxf(L[k][3], fminf(v, L[k][4]));
              L[k][3] = fmaxf(L[k][2], fminf(v, L[k][3]));
              L[k][2] = fmaxf(L[k][1], fminf(v, L[k][2]));
              L[k][1] = fmaxf(L[k][0], fminf(v, L[k][1]));
              L[k][0] = fminf(L[k][0], v);
            }
          }
        }
      }
    }
    __syncthreads();
  }
  float acc = 0.0f;
#pragma unroll
  for (int k = 0; k < 4; ++k)
#pragma unroll
    for (int s = 0; s < 8; ++s) acc += 0.5f - sqrtf(fmaxf(L[k][s], 0.0f));
  if (lane == 0) wsum[wave] = acc;
  __syncthreads();
  if (tid == 0) {
    float s = 0.0f;
#pragma unroll
    for (int w = 0; w < 8; ++w) s += wsum[w];
    block_sum[blockIdx.x] = s;
  }
}

__global__ __launch_bounds__(256) void final_reduce_kernel(
    const float* __restrict__ bs, float* __restrict__ out) {
  const int tid = threadIdx.x;
  float v = bs[tid] + bs[tid + 256];
#pragma unroll
  for (int off = 1; off < 64; off <<= 1) v += __shfl_xor(v, off);
  __shared__ float r[4];
  if ((tid & 63) == 0) r[tid >> 6] = v;
  __syncthreads();
  if (tid == 0) out[0] = (r[0] + r[1] + r[2] + r[3]) * (1.0f / (float)NPTS);
}

extern "C" void kernel_launch(void* const* d_in, const int* in_sizes, int n_in,
                              void* d_out, int out_size, void* d_ws, size_t ws_size,
                              hipStream_t stream) {
  const float* q = (const float*)d_in[0];
  unsigned char* ws = (unsigned char*)d_ws;
  if (ws_size >= WS_REQUIRED) {
    hipMemsetAsync(ws + OFF_COUNTS, 0, 32768, stream);   // counts only
    prep_hist_kernel<<<64, 256, 0, stream>>>(q, ws);
    prep_scan_kernel<<<1, 1024, 0, stream>>>(ws);
    prep_scatter_emit_kernel<<<64, 256, 0, stream>>>(q, ws);
    knn_cells_kernel<<<KNN_GRID, KNN_BLOCK, 0, stream>>>(ws);
    final_reduce2_kernel<<<1, 256, 0, stream>>>(ws, (float*)d_out);
  } else {
    float* block_sum = (float*)d_ws;
    knn_loss_kernel<<<512, 512, 0, stream>>>(q, block_sum);
    final_reduce_kernel<<<1, 256, 0, stream>>>(block_sum, (float*)d_out);
  }
}

// Round 7
// 65.993 us; speedup vs baseline: 2.0406x; 1.0023x over previous
//
#include <hip/hip_runtime.h>

#define NPTS     16384
#define G        20
#define G2       400
#define ORIGIN   -5.0f
#define INV_CELL 2.0f
#define D2MAX    0.25f     // EPS^2 sentinel: contributes exactly 0 after sqrt

#define KNN_GRID  3072     // 12288 waves >= worst-case 12192 entries
#define KNN_BLOCK 256

// ---- ws layout (bytes) ----
#define OFF_COUNTS   0u        // u32[8192]
#define OFF_STARTS   32768u    // u32[8192]
#define OFF_CURSORS  65536u    // u32[8192]
#define OFF_WLCNT    98304u    // u32 (written by scan)
#define OFF_WL       98432u    // int2[12288]  (worst case 12192 entries)
#define OFF_EOFF     196736u   // u32[8192] per-cell entry offset
#define OFF_PTS      262144u   // float4[16384], cell-sorted
#define OFF_CID      524288u   // u32[16384]
#define OFF_PART     589824u   // float[12288] per-entry partials
#define WS_REQUIRED  638976u

// Zero the 32 KB counts array with uint4 stores: 2048 threads x 16 B.
// Replaces hipMemsetAsync whose in-graph fill dispatch measured 39 us.
__global__ __launch_bounds__(256) void prep_zero_kernel(unsigned char* ws) {
  uint4* p = (uint4*)(ws + OFF_COUNTS);
  const int i = blockIdx.x * 256 + threadIdx.x;   // 2048 threads
  p[i] = make_uint4(0u, 0u, 0u, 0u);
}

__global__ __launch_bounds__(256) void prep_hist_kernel(const float* __restrict__ q,
                                                        unsigned char* ws) {
  unsigned* counts  = (unsigned*)(ws + OFF_COUNTS);
  unsigned* cid_arr = (unsigned*)(ws + OFF_CID);
  const int i = blockIdx.x * 256 + threadIdx.x;   // 16384 threads
  const float x = q[3 * i + 0], y = q[3 * i + 1], z = q[3 * i + 2];
  int cx = (int)floorf((x - ORIGIN) * INV_CELL); cx = min(max(cx, 0), G - 1);
  int cy = (int)floorf((y - ORIGIN) * INV_CELL); cy = min(max(cy, 0), G - 1);
  int cz = (int)floorf((z - ORIGIN) * INV_CELL); cz = min(max(cz, 0), G - 1);
  const unsigned cid = (unsigned)((cx * G + cy) * G + cz);
  cid_arr[i] = cid;
  atomicAdd(counts + cid, 1u);
}

// Single block: prefix-sum counts -> starts; zero cursors; per-cell entry
// offsets (pairs: ne = ceil(n/2)); total entry count. NO serial emit here.
__global__ __launch_bounds__(1024) void prep_scan_kernel(unsigned char* ws) {
  unsigned* counts  = (unsigned*)(ws + OFF_COUNTS);
  unsigned* starts  = (unsigned*)(ws + OFF_STARTS);
  unsigned* cursors = (unsigned*)(ws + OFF_CURSORS);
  unsigned* eoff    = (unsigned*)(ws + OFF_EOFF);
  unsigned* wlcnt   = (unsigned*)(ws + OFF_WLCNT);

  __shared__ unsigned scnt[1024], sent[1024];
  const int t = threadIdx.x;
  unsigned c8[8];
  unsigned mycnt = 0, myent = 0;
#pragma unroll
  for (int i = 0; i < 8; ++i) {
    c8[i] = counts[t * 8 + i];
    mycnt += c8[i];
    myent += (c8[i] + 1u) >> 1;
  }
  scnt[t] = mycnt; sent[t] = myent;
  __syncthreads();
  for (int off = 1; off < 1024; off <<= 1) {
    unsigned a = 0, b = 0;
    if (t >= off) { a = scnt[t - off]; b = sent[t - off]; }
    __syncthreads();
    scnt[t] += a; sent[t] += b;
    __syncthreads();
  }
  unsigned run  = scnt[t] - mycnt;   // exclusive prefixes
  unsigned erun = sent[t] - myent;
#pragma unroll
  for (int i = 0; i < 8; ++i) {
    const int c = t * 8 + i;
    starts[c]  = run;
    cursors[c] = 0u;
    eoff[c]    = erun;
    run  += c8[i];
    erun += (c8[i] + 1u) >> 1;
  }
  if (t == 1023) *wlcnt = sent[1023];
}

// Fused: scatter points into cell-sorted order (all 16384 threads) AND emit
// pair-entries per cell (threads < 8192, parallel over cells).
__global__ __launch_bounds__(256) void prep_scatter_emit_kernel(
    const float* __restrict__ q, unsigned char* ws) {
  const unsigned* counts  = (const unsigned*)(ws + OFF_COUNTS);
  const unsigned* starts  = (const unsigned*)(ws + OFF_STARTS);
  unsigned*       cursors = (unsigned*)(ws + OFF_CURSORS);
  const unsigned* eoff    = (const unsigned*)(ws + OFF_EOFF);
  const unsigned* cid_arr = (const unsigned*)(ws + OFF_CID);
  int2*           wl      = (int2*)(ws + OFF_WL);
  float4*         pts     = (float4*)(ws + OFF_PTS);

  const int i = blockIdx.x * 256 + threadIdx.x;   // 16384 threads
  const unsigned cid = cid_arr[i];
  const unsigned pos = starts[cid] + atomicAdd(cursors + cid, 1u);
  pts[pos] = make_float4(q[3 * i + 0], q[3 * i + 1], q[3 * i + 2], 0.0f);

  if (i < 8192) {   // emit this cell's entries (avg ~1.2, max 65 iters)
    const unsigned n = counts[i];
    if (n) {
      const unsigned base = eoff[i];
      const int st = (int)starts[i];
      const unsigned ne = (n + 1u) >> 1;
      for (unsigned g = 0; g < ne; ++g) {
        const unsigned rem = n - 2u * g;
        const int c2 = rem < 2u ? (int)rem : 2;
        wl[base + g] = make_int2(st + 2 * (int)g, (i << 4) | c2);
      }
    }
  }
}

// ONE WAVE per pair-entry (<=2 queries of one cell). No LDS, no barriers,
// no cross-wave merge. Per lane: private sorted top-5 per query (branchless
// med-shift). Epilogue: exact top-8 per query via 8 butterfly extract-min
// rounds over the 64x5 pool (sentinel 0.25 entries contribute exactly 0).
__global__ __launch_bounds__(KNN_BLOCK) void knn_cells_kernel(unsigned char* ws) {
  const unsigned* starts = (const unsigned*)(ws + OFF_STARTS);
  const int2*     wl     = (const int2*)(ws + OFF_WL);
  const float4*   pts    = (const float4*)(ws + OFF_PTS);
  float*          part   = (float*)(ws + OFF_PART);
  const int wlc = (int)*(const unsigned*)(ws + OFF_WLCNT);

  const int lane = threadIdx.x & 63;
  const int e    = blockIdx.x * (KNN_BLOCK / 64) + (threadIdx.x >> 6);
  if (e >= wlc) return;

  // column visit order {dx,dy}: own column first, then faces, then corners
  const unsigned DXC = 10569u;  // {0,1,-1,0,0,1,1,-1,-1}
  const unsigned DYC = 34965u;  // {0,0,0,1,-1,1,-1,1,-1}

  const int2 ent   = wl[e];
  const int qstart = ent.x;
  const int cell   = ent.y >> 4;
  const int cnt    = ent.y & 15;   // 1 or 2

  float qx[2], qy[2], qz[2];
#pragma unroll
  for (int k = 0; k < 2; ++k) {
    if (k < cnt) {
      const float4 Q = pts[qstart + k];
      qx[k] = Q.x; qy[k] = Q.y; qz[k] = Q.z;
    } else {  // dummy query far away: never passes threshold
      qx[k] = 1.0e4f; qy[k] = 1.0e4f; qz[k] = 1.0e4f;
    }
  }

  float P[2][5];
#pragma unroll
  for (int k = 0; k < 2; ++k)
#pragma unroll
    for (int s = 0; s < 5; ++s) P[k][s] = D2MAX;

  const int cx  = cell / G2;
  const int rem = cell - cx * G2;
  const int cy  = rem / G;
  const int cz  = rem - cy * G;
  const int zlo = cz > 0 ? cz - 1 : 0;
  const int zhi = cz < G - 1 ? cz + 1 : G - 1;

  // Prefetch all 9 column range bounds (independent loads, one latency wall)
  int rs[9], re[9];
#pragma unroll
  for (int r = 0; r < 9; ++r) {
    const int dx = (int)((DXC >> (2 * r)) & 3u) - 1;
    const int dy = (int)((DYC >> (2 * r)) & 3u) - 1;
    const int nx = cx + dx, ny = cy + dy;
    if ((unsigned)nx < (unsigned)G && (unsigned)ny < (unsigned)G) {
      const int colbase = (nx * G + ny) * G;
      rs[r] = (int)starts[colbase + zlo];
      re[r] = (int)starts[colbase + zhi + 1];
    } else {
      rs[r] = 0; re[r] = 0;
    }
  }

#pragma unroll
  for (int r = 0; r < 9; ++r) {
    for (int j = rs[r]; j < re[r]; j += 64) {
      int idx = j + lane;
      const bool val = idx < re[r];
      if (!val) idx = re[r] - 1;
      const float4 Pt = pts[idx];
#pragma unroll
      for (int k = 0; k < 2; ++k) {
        const float ddx = qx[k] - Pt.x;
        const float ddy = qy[k] - Pt.y;
        const float ddz = qz[k] - Pt.z;
        float v = fmaf(ddz, ddz, fmaf(ddy, ddy, ddx * ddx));
        if (!val) v = 1.0e9f;
        if (v < P[k][4] && v != 0.0f) {   // self -> exactly 0, excluded
          P[k][4] = fmaxf(P[k][3], fminf(v, P[k][4]));
          P[k][3] = fmaxf(P[k][2], fminf(v, P[k][3]));
          P[k][2] = fmaxf(P[k][1], fminf(v, P[k][2]));
          P[k][1] = fmaxf(P[k][0], fminf(v, P[k][1]));
          P[k][0] = fminf(P[k][0], v);
        }
      }
    }
  }

  // Epilogue: per query, sum relu-contributions of the 8 smallest of the
  // 64x5 pool. m <= 0.25 always; sentinel -> +0. Ascending -> deterministic.
  float accE = 0.0f;
#pragma unroll
  for (int k = 0; k < 2; ++k) {
    if (k < cnt) {
      float a0 = P[k][0], a1 = P[k][1], a2 = P[k][2], a3 = P[k][3], a4 = P[k][4];
#pragma unroll
      for (int rr = 0; rr < 8; ++rr) {
        float m = a0;
        m = fminf(m, __shfl_xor(m, 1));
        m = fminf(m, __shfl_xor(m, 2));
        m = fminf(m, __shfl_xor(m, 4));
        m = fminf(m, __shfl_xor(m, 8));
        m = fminf(m, __shfl_xor(m, 16));
        m = fminf(m, __shfl_xor(m, 32));
        accE += 0.5f - sqrtf(m);
        const unsigned long long bal = __ballot(a0 == m);
        const int first = __ffsll(bal) - 1;
        const bool adv = (lane == first);
        a0 = adv ? a1 : a0;
        a1 = adv ? a2 : a1;
        a2 = adv ? a3 : a2;
        a3 = adv ? a4 : a3;
        a4 = adv ? D2MAX : a4;
      }
    }
  }

  if (lane == 0) part[e] = accE;
}

__global__ __launch_bounds__(256) void final_reduce2_kernel(const unsigned char* ws,
                                                            float* __restrict__ out) {
  const float* part = (const float*)(ws + OFF_PART);
  const int wlc = (int)*(const unsigned*)(ws + OFF_WLCNT);
  const int tid = threadIdx.x;
  float v = 0.0f;
  for (int i = tid; i < wlc; i += 256) v += part[i];
#pragma unroll
  for (int off = 1; off < 64; off <<= 1) v += __shfl_xor(v, off);
  __shared__ float r[4];
  if ((tid & 63) == 0) r[tid >> 6] = v;
  __syncthreads();
  if (tid == 0) out[0] = (r[0] + r[1] + r[2] + r[3]) * (1.0f / (float)NPTS);
}

// ---------------- v2 fallback (proven) if ws is too small ----------------
#define FB_TILE 2048
__global__ __launch_bounds__(512) void knn_loss_kernel(
    const float* __restrict__ q, float* __restrict__ block_sum) {
  __shared__ float4 tile[FB_TILE];
  __shared__ float  wsum[8];
  const int tid = threadIdx.x, lane = tid & 63, wave = tid >> 6;
  const int qbase = blockIdx.x * 32 + wave * 4;
  float qx[4], qy[4], qz[4], qq[4];
#pragma unroll
  for (int k = 0; k < 4; ++k) {
    const float x = q[3 * (qbase + k) + 0];
    const float y = q[3 * (qbase + k) + 1];
    const float z = q[3 * (qbase + k) + 2];
    qx[k] = x; qy[k] = y; qz[k] = z;
    qq[k] = fmaf(z, z, fmaf(y, y, x * x));
  }
  float L[4][8];
#pragma unroll
  for (int k = 0; k < 4; ++k)
#pragma unroll
    for (int s = 0; s < 8; ++s) L[k][s] = D2MAX;
  for (int t = 0; t < NPTS / FB_TILE; ++t) {
    const int tb = t * FB_TILE;
#pragma unroll
    for (int s2 = 0; s2 < FB_TILE / 512; ++s2) {
      const int p = s2 * 512 + tid, gp = tb + p;
      const float x = q[3 * gp], y = q[3 * gp + 1], z = q[3 * gp + 2];
      tile[p] = make_float4(x, y, z, fmaf(z, z, fmaf(y, y, x * x)));
    }
    __syncthreads();
#pragma unroll 2
    for (int s = 0; s < FB_TILE / 64; ++s) {
      const float4 p = tile[s * 64 + lane];
      float d2[4];
#pragma unroll
      for (int k = 0; k < 4; ++k) {
        const float dt = fmaf(qx[k], p.x, fmaf(qy[k], p.y, qz[k] * p.z));
        d2[k] = fmaf(-2.0f, dt, qq[k] + p.w);
      }
      unsigned long long m[4];
#pragma unroll
      for (int k = 0; k < 4; ++k) m[k] = __ballot(d2[k] < L[k][7]);
      if (m[0] | m[1] | m[2] | m[3]) {
        const int jb = tb + s * 64;
#pragma unroll
        for (int k = 0; k < 4; ++k) {
          unsigned long long mk = m[k];
          while (mk) {
            const int i = __ffsll(mk) - 1;
            mk &= mk - 1;
            const float v = __shfl(d2[k], i);
            if ((jb + i) != (qbase + k) && v < L[k][7]) {
              L[k][7] = fmaxf(L[k][6], fminf(v, L[k][7]));
              L[k][6] = fmaxf(L[k][5], fminf(v, L[k][6]));
              L[k][5] = fmaxf(L[k][4], fminf(v, L[k][5]));
              L[k][4] = fmaxf(L[k][3], fminf(v, L[k][4]));
              L[k][3] = fmaxf(L[k][2], fminf(v, L[k][3]));
              L[k][2] = fmaxf(L[k][1], fminf(v, L[k][2]));
              L[k][1] = fmaxf(L[k][0], fminf(v, L[k][1]));
              L[k][0] = fminf(L[k][0], v);
            }
          }
        }
      }
    }
    __syncthreads();
  }
  float acc = 0.0f;
#pragma unroll
  for (int k = 0; k < 4; ++k)
#pragma unroll
    for (int s = 0; s < 8; ++s) acc += 0.5f - sqrtf(fmaxf(L[k][s], 0.0f));
  if (lane == 0) wsum[wave] = acc;
  __syncthreads();
  if (tid == 0) {
    float s = 0.0f;
#pragma unroll
    for (int w = 0; w < 8; ++w) s += wsum[w];
    block_sum[blockIdx.x] = s;
  }
}

__global__ __launch_bounds__(256) void final_reduce_kernel(
    const float* __restrict__ bs, float* __restrict__ out) {
  const int tid = threadIdx.x;
  float v = bs[tid] + bs[tid + 256];
#pragma unroll
  for (int off = 1; off < 64; off <<= 1) v += __shfl_xor(v, off);
  __shared__ float r[4];
  if ((tid & 63) == 0) r[tid >> 6] = v;
  __syncthreads();
  if (tid == 0) out[0] = (r[0] + r[1] + r[2] + r[3]) * (1.0f / (float)NPTS);
}

extern "C" void kernel_launch(void* const* d_in, const int* in_sizes, int n_in,
                              void* d_out, int out_size, void* d_ws, size_t ws_size,
                              hipStream_t stream) {
  const float* q = (const float*)d_in[0];
  unsigned char* ws = (unsigned char*)d_ws;
  if (ws_size >= WS_REQUIRED) {
    prep_zero_kernel<<<8, 256, 0, stream>>>(ws);
    prep_hist_kernel<<<64, 256, 0, stream>>>(q, ws);
    prep_scan_kernel<<<1, 1024, 0, stream>>>(ws);
    prep_scatter_emit_kernel<<<64, 256, 0, stream>>>(q, ws);
    knn_cells_kernel<<<KNN_GRID, KNN_BLOCK, 0, stream>>>(ws);
    final_reduce2_kernel<<<1, 256, 0, stream>>>(ws, (float*)d_out);
  } else {
    float* block_sum = (float*)d_ws;
    knn_loss_kernel<<<512, 512, 0, stream>>>(q, block_sum);
    final_reduce_kernel<<<1, 256, 0, stream>>>(block_sum, (float*)d_out);
  }
}